// Round 9
// baseline (534.778 us; speedup 1.0000x reference)
//
#include <hip/hip_runtime.h>

#define N_NODES 50000
#define M_PAD 50048            // 391 * 128
#define MT 391
#define F_IN 256
#define F_H 128
#define F_OUT 64
#define E_MAX 1600000
#define NEG_SLOPE 0.2f
#define EPS_F 1e-16f
#define NPART 196              // ceil(50000/256)
#define NBUCK 196              // coarse buckets: dst >> 8
#define CH_E 8192              // edges per sortA block -> 196 blocks

typedef __bf16 bf16x8 __attribute__((ext_vector_type(8)));
typedef float f32x4 __attribute__((ext_vector_type(4)));

// ---------------- device-global scratch ------------------------------------
__device__ unsigned short g_B1h[256 * 256];
__device__ unsigned short g_B1l[256 * 256];
__device__ unsigned short g_B2h[128 * 128];
__device__ unsigned short g_B2l[128 * 128];
__device__ unsigned short g_x1h[(size_t)M_PAD * F_IN];
__device__ unsigned short g_x1l[(size_t)M_PAD * F_IN];
__device__ unsigned short g_hh[(size_t)M_PAD * F_H];
__device__ unsigned short g_hl[(size_t)M_PAD * F_H];
// gather tables: xl in bf16 (halves gather bytes), xr in f32 (read once/dst)
__device__ unsigned short g_xl1b[(size_t)N_NODES * F_H];
__device__ float g_xr1[(size_t)N_NODES * F_H];
__device__ unsigned short g_xl2b[(size_t)N_NODES * F_OUT];
__device__ float g_xr2[(size_t)N_NODES * F_OUT];
// CSR by dst
__device__ unsigned g_cnt[N_NODES];
__device__ unsigned g_part[NPART];
__device__ unsigned g_rowstart[N_NODES + 1];
__device__ unsigned g_bcursor[NBUCK];
__device__ unsigned g_bucketed[E_MAX];     // packed src | dst<<16
__device__ int g_src_sorted[E_MAX];

// ---------------- helpers ---------------------------------------------------
__device__ inline float san(float v) { return fminf(fmaxf(v, -64.f), 64.f); }
__device__ inline float lrelu(float z) { return fmaxf(z, NEG_SLOPE * z); }
__device__ inline unsigned short f2bf(float f) {        // RNE f32->bf16
    unsigned u = __float_as_uint(f);
    return (unsigned short)((u + 0x7fffu + ((u >> 16) & 1u)) >> 16);
}
__device__ inline float bf2f(unsigned short h) {
    return __uint_as_float(((unsigned)h) << 16);
}
__device__ inline float blo(unsigned w) { return __uint_as_float(w << 16); }
__device__ inline float bhi(unsigned w) { return __uint_as_float(w & 0xffff0000u); }

// ---------------- weight prepack + csr_zero (fused) -------------------------
__global__ void wconv_all(const float* __restrict__ Wl1,
                          const float* __restrict__ Wr1,
                          const float* __restrict__ Wl2,
                          const float* __restrict__ Wr2) {
    int i = blockIdx.x * blockDim.x + threadIdx.x;
    if (i < N_NODES) g_cnt[i] = 0u;                    // fused csr_zero
    if (i < 256 * 256) {
        int n = i >> 8, k = i & 255;
        float v = san((n < 128) ? Wl1[k * 128 + n] : Wr1[k * 128 + (n - 128)]);
        unsigned short h = f2bf(v);
        g_B1h[n * 256 + k] = h;
        g_B1l[n * 256 + k] = f2bf(v - bf2f(h));
    }
    if (i < 128 * 128) {
        int n = i >> 7, k = i & 127;
        float v = san((n < 64) ? Wl2[k * 64 + n] : Wr2[k * 64 + (n - 64)]);
        unsigned short h = f2bf(v);
        g_B2h[n * 128 + k] = h;
        g_B2l[n * 128 + k] = f2bf(v - bf2f(h));
    }
}

// ---------------- x split + h pad-row zero (fused) --------------------------
__global__ void split_x(const float* __restrict__ x) {
    int i = blockIdx.x * 256 + threadIdx.x;
    if (i < (M_PAD - N_NODES) * F_H) {                 // fused pad_h
        g_hh[(size_t)N_NODES * F_H + i] = 0;
        g_hl[(size_t)N_NODES * F_H + i] = 0;
    }
    int m = i >> 6, c4 = i & 63;
    float4 v = make_float4(0.f, 0.f, 0.f, 0.f);
    if (m < N_NODES) v = ((const float4*)(x + (size_t)m * F_IN))[c4];
    v.x = san(v.x); v.y = san(v.y); v.z = san(v.z); v.w = san(v.w);
    unsigned short h0 = f2bf(v.x), h1 = f2bf(v.y), h2 = f2bf(v.z), h3 = f2bf(v.w);
    unsigned short l0 = f2bf(v.x - bf2f(h0)), l1 = f2bf(v.y - bf2f(h1));
    unsigned short l2 = f2bf(v.z - bf2f(h2)), l3 = f2bf(v.w - bf2f(h3));
    size_t o = (size_t)m * F_IN + c4 * 4;
    uint2 ph = make_uint2(((unsigned)h1 << 16) | h0, ((unsigned)h3 << 16) | h2);
    uint2 pl = make_uint2(((unsigned)l1 << 16) | l0, ((unsigned)l3 << 16) | l2);
    *(uint2*)(g_x1h + o) = ph;
    *(uint2*)(g_x1l + o) = pl;
}

// ---------------- CSR build --------------------------------------------------
__global__ void csr_hist(const int* __restrict__ dst, int E) {
    int e = blockIdx.x * blockDim.x + threadIdx.x;
    if (e < E) atomicAdd(&g_cnt[dst[e]], 1u);
}
__global__ __launch_bounds__(256) void scanA() {
    int i = blockIdx.x * 256 + threadIdx.x;
    unsigned v = (i < N_NODES) ? g_cnt[i] : 0u;
#pragma unroll
    for (int off = 32; off > 0; off >>= 1) v += __shfl_xor(v, off, 64);
    __shared__ unsigned ws[4];
    if ((threadIdx.x & 63) == 0) ws[threadIdx.x >> 6] = v;
    __syncthreads();
    if (threadIdx.x == 0) g_part[blockIdx.x] = ws[0] + ws[1] + ws[2] + ws[3];
}
__global__ __launch_bounds__(256) void scanB(int E) {
    __shared__ unsigned lds[256];
    int t = threadIdx.x;
    unsigned v = (t < NPART) ? g_part[t] : 0u;
    lds[t] = v;
    __syncthreads();
    for (int off = 1; off < 256; off <<= 1) {
        unsigned u = (t >= off) ? lds[t - off] : 0u;
        __syncthreads();
        lds[t] += u;
        __syncthreads();
    }
    if (t < NPART) {
        unsigned excl = lds[t] - v;
        g_part[t] = excl;
        g_bcursor[t] = excl;               // fused binit (bucket start == part)
    }
    if (t == 0) g_rowstart[N_NODES] = (unsigned)E;
}
__global__ __launch_bounds__(256) void scanC() {
    __shared__ unsigned lds[256];
    int t = threadIdx.x;
    int i = blockIdx.x * 256 + t;
    unsigned v = (i < N_NODES) ? g_cnt[i] : 0u;
    lds[t] = v;
    __syncthreads();
    for (int off = 1; off < 256; off <<= 1) {
        unsigned u = (t >= off) ? lds[t - off] : 0u;
        __syncthreads();
        lds[t] += u;
        __syncthreads();
    }
    if (i < N_NODES) g_rowstart[i] = lds[t] - v + g_part[blockIdx.x];
}

// ---------------- two-pass locality-aware sort ------------------------------
// Pass A: per-WAVE histograms + cursors (4x less LDS-atomic contention).
__global__ __launch_bounds__(256) void sortA(const int* __restrict__ src,
                                             const int* __restrict__ dst, int E) {
    __shared__ unsigned l_cnt[4][NBUCK];   // counts, then per-wave cursors
    int t = threadIdx.x, w = t >> 6;
    int e0 = blockIdx.x * CH_E;
    int e1 = min(e0 + CH_E, E);
    for (int i = t; i < 4 * NBUCK; i += 256) (&l_cnt[0][0])[i] = 0u;
    __syncthreads();
    for (int e = e0 + t; e < e1; e += 256)
        atomicAdd(&l_cnt[w][dst[e] >> 8], 1u);
    __syncthreads();
    for (int b = t; b < NBUCK; b += 256) {
        unsigned c0 = l_cnt[0][b], c1 = l_cnt[1][b], c2 = l_cnt[2][b], c3 = l_cnt[3][b];
        unsigned tot = c0 + c1 + c2 + c3;
        unsigned base = tot ? atomicAdd(&g_bcursor[b], tot) : 0u;
        l_cnt[0][b] = base;
        l_cnt[1][b] = base + c0;
        l_cnt[2][b] = base + c0 + c1;
        l_cnt[3][b] = base + c0 + c1 + c2;
    }
    __syncthreads();
    for (int e = e0 + t; e < e1; e += 256) {
        int d = dst[e];
        int b = d >> 8;
        unsigned pos = atomicAdd(&l_cnt[w][b], 1u);
        g_bucketed[pos] = (unsigned)src[e] | ((unsigned)d << 16);
    }
}
__global__ __launch_bounds__(256) void sortB() {
    __shared__ unsigned l_cur[256];
    int b = blockIdx.x;
    int d0 = b * 256;
    int t = threadIdx.x;
    l_cur[t] = g_rowstart[min(d0 + t, N_NODES)];
    unsigned bstart = g_rowstart[min(d0, N_NODES)];
    unsigned bend   = g_rowstart[min(d0 + 256, N_NODES)];
    __syncthreads();
    for (unsigned i = bstart + t; i < bend; i += 256) {
        unsigned e = g_bucketed[i];
        unsigned d = e >> 16;
        unsigned pos = atomicAdd(&l_cur[d - d0], 1u);
        g_src_sorted[pos] = (int)(e & 0xFFFFu);
    }
}

// ---------------- split-bf16 MFMA GEMM (register double-buffer) -------------
template<int LAYER>
__global__ __launch_bounds__(256) void gemm_mfma() {
    constexpr int K    = (LAYER == 1) ? 256 : 128;
    constexpr int NSPL = (LAYER == 1) ? 128 : 64;
    const unsigned short* __restrict__ Ah = (LAYER == 1) ? g_x1h : g_hh;
    const unsigned short* __restrict__ Al = (LAYER == 1) ? g_x1l : g_hl;
    const unsigned short* __restrict__ Bh = (LAYER == 1) ? g_B1h : g_B2h;
    const unsigned short* __restrict__ Bl = (LAYER == 1) ? g_B1l : g_B2l;
    unsigned short* __restrict__ OL = (LAYER == 1) ? g_xl1b : g_xl2b;
    float* __restrict__ OR_ = (LAYER == 1) ? g_xr1 : g_xr2;

    __shared__ __align__(16) unsigned short As_h[128][40];
    __shared__ __align__(16) unsigned short As_l[128][40];
    __shared__ __align__(16) unsigned short Bs_h[128][40];
    __shared__ __align__(16) unsigned short Bs_l[128][40];

    const int m0 = blockIdx.x * 128;
    const int n0 = blockIdx.y * 128;
    const int t = threadIdx.x;
    const int wave = t >> 6, lane = t & 63;
    const int wm = (wave >> 1) * 64, wn = (wave & 1) * 64;
    const int lr = lane & 15, g8 = (lane >> 4) * 8;
    const int srow = t >> 1, shalf = (t & 1) * 16;

    f32x4 acc[4][4];
#pragma unroll
    for (int i = 0; i < 4; ++i)
#pragma unroll
        for (int j = 0; j < 4; ++j) acc[i][j] = (f32x4){0.f, 0.f, 0.f, 0.f};

    const size_t gabase = (size_t)(m0 + srow) * K + shalf;
    const size_t gbbase = (size_t)(n0 + srow) * K + shalf;

    uint4 P[8];
    // prologue: tile kb=0 into registers
    P[0] = *(const uint4*)(Ah + gabase);     P[1] = *(const uint4*)(Ah + gabase + 8);
    P[2] = *(const uint4*)(Al + gabase);     P[3] = *(const uint4*)(Al + gabase + 8);
    P[4] = *(const uint4*)(Bh + gbbase);     P[5] = *(const uint4*)(Bh + gbbase + 8);
    P[6] = *(const uint4*)(Bl + gbbase);     P[7] = *(const uint4*)(Bl + gbbase + 8);

#pragma unroll
    for (int kb = 0; kb < K; kb += 32) {
        __syncthreads();                     // prev-iter LDS consumers done
        *(uint4*)&As_h[srow][shalf]     = P[0];
        *(uint4*)&As_h[srow][shalf + 8] = P[1];
        *(uint4*)&As_l[srow][shalf]     = P[2];
        *(uint4*)&As_l[srow][shalf + 8] = P[3];
        *(uint4*)&Bs_h[srow][shalf]     = P[4];
        *(uint4*)&Bs_h[srow][shalf + 8] = P[5];
        *(uint4*)&Bs_l[srow][shalf]     = P[6];
        *(uint4*)&Bs_l[srow][shalf + 8] = P[7];
        __syncthreads();
        if (kb + 32 < K) {                   // prefetch next tile: overlaps MFMA
            size_t ga = gabase + kb + 32, gb = gbbase + kb + 32;
            P[0] = *(const uint4*)(Ah + ga); P[1] = *(const uint4*)(Ah + ga + 8);
            P[2] = *(const uint4*)(Al + ga); P[3] = *(const uint4*)(Al + ga + 8);
            P[4] = *(const uint4*)(Bh + gb); P[5] = *(const uint4*)(Bh + gb + 8);
            P[6] = *(const uint4*)(Bl + gb); P[7] = *(const uint4*)(Bl + gb + 8);
        }

        bf16x8 af_h[4], af_l[4], bf_h[4], bf_l[4];
#pragma unroll
        for (int i = 0; i < 4; ++i) {
            af_h[i] = *(const bf16x8*)&As_h[wm + i * 16 + lr][g8];
            af_l[i] = *(const bf16x8*)&As_l[wm + i * 16 + lr][g8];
        }
#pragma unroll
        for (int j = 0; j < 4; ++j) {
            bf_h[j] = *(const bf16x8*)&Bs_h[wn + j * 16 + lr][g8];
            bf_l[j] = *(const bf16x8*)&Bs_l[wn + j * 16 + lr][g8];
        }
#pragma unroll
        for (int i = 0; i < 4; ++i)
#pragma unroll
            for (int j = 0; j < 4; ++j) {
                acc[i][j] = __builtin_amdgcn_mfma_f32_16x16x32_bf16(af_h[i], bf_h[j], acc[i][j], 0, 0, 0);
                acc[i][j] = __builtin_amdgcn_mfma_f32_16x16x32_bf16(af_h[i], bf_l[j], acc[i][j], 0, 0, 0);
                acc[i][j] = __builtin_amdgcn_mfma_f32_16x16x32_bf16(af_l[i], bf_h[j], acc[i][j], 0, 0, 0);
            }
    }

    const int drow = (lane >> 4) * 4;
#pragma unroll
    for (int i = 0; i < 4; ++i)
#pragma unroll
        for (int j = 0; j < 4; ++j) {
            int gn = n0 + wn + j * 16 + lr;
#pragma unroll
            for (int r = 0; r < 4; ++r) {
                int m = m0 + wm + i * 16 + drow + r;
                if (m < N_NODES) {
                    if (gn < NSPL) OL[(size_t)m * NSPL + gn] = f2bf(acc[i][j][r]);
                    else           OR_[(size_t)m * NSPL + (gn - NSPL)] = acc[i][j][r];
                }
            }
        }
}

// ---------------- fused attention+aggregate, layer 1 ------------------------
__global__ __launch_bounds__(256) void att_agg1(const float* __restrict__ att,
                                                const float* __restrict__ bias) {
    __shared__ float s_out[4][F_H];
    int wid = threadIdx.x >> 6, lane = threadIdx.x & 63;
    int w = blockIdx.x * 4 + wid;
    int g = lane >> 3;
    int fi = lane & 7;
    int f0 = fi * 16;

    float4 xr[4], at[4];
    const float4* xrp = (const float4*)(g_xr1 + (size_t)w * F_H + f0);
    const float4* atp = (const float4*)(att + f0);
#pragma unroll
    for (int q = 0; q < 4; ++q) {
        xr[q] = xrp[q];
        float4 a = atp[q];
        a.x = san(a.x); a.y = san(a.y); a.z = san(a.z); a.w = san(a.w);
        at[q] = a;
    }

    int beg = (int)g_rowstart[w], end = (int)g_rowstart[w + 1];
    float m = -INFINITY, ssum = 0.f;
    float4 acc[4];
#pragma unroll
    for (int q = 0; q < 4; ++q) acc[q] = make_float4(0.f, 0.f, 0.f, 0.f);

    for (int c0 = beg; c0 < end; c0 += 64) {
        int nc = min(64, end - c0);
        int mysrc = (lane < nc) ? g_src_sorted[c0 + lane] : 0;
        for (int r0 = 0; r0 < nc; r0 += 8) {
            int eidx = r0 + g;
            bool valid = eidx < nc;
            int s = __shfl(mysrc, eidx, 64);
            const uint4* rowp = (const uint4*)(g_xl1b + (size_t)s * F_H + f0);
            uint4 u0 = rowp[0], u1 = rowp[1];
            float4 row[4];
            row[0] = make_float4(blo(u0.x), bhi(u0.x), blo(u0.y), bhi(u0.y));
            row[1] = make_float4(blo(u0.z), bhi(u0.z), blo(u0.w), bhi(u0.w));
            row[2] = make_float4(blo(u1.x), bhi(u1.x), blo(u1.y), bhi(u1.y));
            row[3] = make_float4(blo(u1.z), bhi(u1.z), blo(u1.w), bhi(u1.w));
            float d = 0.f;
#pragma unroll
            for (int q = 0; q < 4; ++q) {
                float z;
                z = row[q].x + xr[q].x; d = fmaf(lrelu(z), at[q].x, d);
                z = row[q].y + xr[q].y; d = fmaf(lrelu(z), at[q].y, d);
                z = row[q].z + xr[q].z; d = fmaf(lrelu(z), at[q].z, d);
                z = row[q].w + xr[q].w; d = fmaf(lrelu(z), at[q].w, d);
            }
            d += __shfl_xor(d, 1, 64);
            d += __shfl_xor(d, 2, 64);
            d += __shfl_xor(d, 4, 64);
            float e = valid ? d : -INFINITY;
            float M = e;
            M = fmaxf(M, __shfl_xor(M, 8, 64));
            M = fmaxf(M, __shfl_xor(M, 16, 64));
            M = fmaxf(M, __shfl_xor(M, 32, 64));
            if (M > m) {                      // wave-uniform; skipping is exact
                float sc = __expf(m - M);     // 0 on first round (m=-inf)
                m = M;
                ssum *= sc;
#pragma unroll
                for (int q = 0; q < 4; ++q) {
                    acc[q].x *= sc; acc[q].y *= sc;
                    acc[q].z *= sc; acc[q].w *= sc;
                }
            }
            float p = __expf(e - m);          // 0 for invalid edges
            ssum += p;
#pragma unroll
            for (int q = 0; q < 4; ++q) {
                acc[q].x = fmaf(p, row[q].x, acc[q].x);
                acc[q].y = fmaf(p, row[q].y, acc[q].y);
                acc[q].z = fmaf(p, row[q].z, acc[q].z);
                acc[q].w = fmaf(p, row[q].w, acc[q].w);
            }
        }
    }
#pragma unroll
    for (int off = 8; off < 64; off <<= 1) {
        ssum += __shfl_xor(ssum, off, 64);
#pragma unroll
        for (int q = 0; q < 4; ++q) {
            acc[q].x += __shfl_xor(acc[q].x, off, 64);
            acc[q].y += __shfl_xor(acc[q].y, off, 64);
            acc[q].z += __shfl_xor(acc[q].z, off, 64);
            acc[q].w += __shfl_xor(acc[q].w, off, 64);
        }
    }
    float inv = 1.f / (ssum + EPS_F);
    if (g == 0) {
        float4* op = (float4*)&s_out[wid][f0];
#pragma unroll
        for (int q = 0; q < 4; ++q) {
            float4 v;
            v.x = acc[q].x * inv; v.y = acc[q].y * inv;
            v.z = acc[q].z * inv; v.w = acc[q].w * inv;
            op[q] = v;
        }
    }
    __syncthreads();
    int f2 = lane * 2;
    float2 o = *(float2*)&s_out[wid][f2];
    o.x = fmaxf(o.x + san(bias[f2]), 0.f);
    o.y = fmaxf(o.y + san(bias[f2 + 1]), 0.f);
    unsigned short hx = f2bf(o.x), hy = f2bf(o.y);
    unsigned short lx = f2bf(o.x - bf2f(hx)), ly = f2bf(o.y - bf2f(hy));
    size_t base = (size_t)w * F_H + f2;
    *(unsigned*)(g_hh + base) = ((unsigned)hy << 16) | hx;
    *(unsigned*)(g_hl + base) = ((unsigned)ly << 16) | lx;
}

// ---------------- fused attention+aggregate, layer 2 (F=64) -----------------
__global__ __launch_bounds__(256) void att_agg2(const float* __restrict__ att,
                                                const float* __restrict__ bias,
                                                float* __restrict__ out) {
    __shared__ float s_out[4][F_OUT];
    int wid = threadIdx.x >> 6, lane = threadIdx.x & 63;
    int w = blockIdx.x * 4 + wid;
    int g = lane >> 3;
    int fi = lane & 7;
    int f0 = fi * 8;

    float4 xr[2], at[2];
    const float4* xrp = (const float4*)(g_xr2 + (size_t)w * F_OUT + f0);
    const float4* atp = (const float4*)(att + f0);
#pragma unroll
    for (int q = 0; q < 2; ++q) {
        xr[q] = xrp[q];
        float4 a = atp[q];
        a.x = san(a.x); a.y = san(a.y); a.z = san(a.z); a.w = san(a.w);
        at[q] = a;
    }

    int beg = (int)g_rowstart[w], end = (int)g_rowstart[w + 1];
    float m = -INFINITY, ssum = 0.f;
    float4 acc[2];
#pragma unroll
    for (int q = 0; q < 2; ++q) acc[q] = make_float4(0.f, 0.f, 0.f, 0.f);

    for (int c0 = beg; c0 < end; c0 += 64) {
        int nc = min(64, end - c0);
        int mysrc = (lane < nc) ? g_src_sorted[c0 + lane] : 0;
        for (int r0 = 0; r0 < nc; r0 += 8) {
            int eidx = r0 + g;
            bool valid = eidx < nc;
            int s = __shfl(mysrc, eidx, 64);
            uint4 u0 = *(const uint4*)(g_xl2b + (size_t)s * F_OUT + f0);
            float4 row[2];
            row[0] = make_float4(blo(u0.x), bhi(u0.x), blo(u0.y), bhi(u0.y));
            row[1] = make_float4(blo(u0.z), bhi(u0.z), blo(u0.w), bhi(u0.w));
            float d = 0.f;
#pragma unroll
            for (int q = 0; q < 2; ++q) {
                float z;
                z = row[q].x + xr[q].x; d = fmaf(lrelu(z), at[q].x, d);
                z = row[q].y + xr[q].y; d = fmaf(lrelu(z), at[q].y, d);
                z = row[q].z + xr[q].z; d = fmaf(lrelu(z), at[q].z, d);
                z = row[q].w + xr[q].w; d = fmaf(lrelu(z), at[q].w, d);
            }
            d += __shfl_xor(d, 1, 64);
            d += __shfl_xor(d, 2, 64);
            d += __shfl_xor(d, 4, 64);
            float e = valid ? d : -INFINITY;
            float M = e;
            M = fmaxf(M, __shfl_xor(M, 8, 64));
            M = fmaxf(M, __shfl_xor(M, 16, 64));
            M = fmaxf(M, __shfl_xor(M, 32, 64));
            if (M > m) {
                float sc = __expf(m - M);
                m = M;
                ssum *= sc;
#pragma unroll
                for (int q = 0; q < 2; ++q) {
                    acc[q].x *= sc; acc[q].y *= sc;
                    acc[q].z *= sc; acc[q].w *= sc;
                }
            }
            float p = __expf(e - m);
            ssum += p;
#pragma unroll
            for (int q = 0; q < 2; ++q) {
                acc[q].x = fmaf(p, row[q].x, acc[q].x);
                acc[q].y = fmaf(p, row[q].y, acc[q].y);
                acc[q].z = fmaf(p, row[q].z, acc[q].z);
                acc[q].w = fmaf(p, row[q].w, acc[q].w);
            }
        }
    }
#pragma unroll
    for (int off = 8; off < 64; off <<= 1) {
        ssum += __shfl_xor(ssum, off, 64);
#pragma unroll
        for (int q = 0; q < 2; ++q) {
            acc[q].x += __shfl_xor(acc[q].x, off, 64);
            acc[q].y += __shfl_xor(acc[q].y, off, 64);
            acc[q].z += __shfl_xor(acc[q].z, off, 64);
            acc[q].w += __shfl_xor(acc[q].w, off, 64);
        }
    }
    float inv = 1.f / (ssum + EPS_F);
    if (g == 0) {
        float4* op = (float4*)&s_out[wid][f0];
#pragma unroll
        for (int q = 0; q < 2; ++q) {
            float4 v;
            v.x = acc[q].x * inv; v.y = acc[q].y * inv;
            v.z = acc[q].z * inv; v.w = acc[q].w * inv;
            op[q] = v;
        }
    }
    __syncthreads();
    out[(size_t)w * F_OUT + lane] = s_out[wid][lane] + san(bias[lane]);
}

// ---------------- launch ------------------------------------------------------
extern "C" void kernel_launch(void* const* d_in, const int* in_sizes, int n_in,
                              void* d_out, int out_size, void* d_ws, size_t ws_size,
                              hipStream_t stream) {
    const float* x    = (const float*)d_in[0];
    const int*   ei   = (const int*)d_in[1];
    const float* Wl1  = (const float*)d_in[2];
    const float* Wr1  = (const float*)d_in[3];
    const float* att1 = (const float*)d_in[4];
    const float* b1   = (const float*)d_in[5];
    const float* Wl2  = (const float*)d_in[6];
    const float* Wr2  = (const float*)d_in[7];
    const float* att2 = (const float*)d_in[8];
    const float* b2   = (const float*)d_in[9];

    int E = in_sizes[1] / 2;
    const int* src = ei;
    const int* dst = ei + E;

    int gE = (E + 255) / 256;
    int gN = N_NODES / 4;
    int gSX = (M_PAD * (F_IN / 4)) / 256;
    int gSA = (E + CH_E - 1) / CH_E;

    wconv_all<<<256, 256, 0, stream>>>(Wl1, Wr1, Wl2, Wr2);   // + csr_zero
    split_x<<<gSX, 256, 0, stream>>>(x);                      // + pad_h

    csr_hist<<<gE, 256, 0, stream>>>(dst, E);
    scanA<<<NPART, 256, 0, stream>>>();
    scanB<<<1, 256, 0, stream>>>(E);                          // + binit
    scanC<<<NPART, 256, 0, stream>>>();
    sortA<<<gSA, 256, 0, stream>>>(src, dst, E);
    sortB<<<NBUCK, 256, 0, stream>>>();

    // ---- layer 1 ----
    gemm_mfma<1><<<dim3(MT, 2), 256, 0, stream>>>();
    att_agg1<<<gN, 256, 0, stream>>>(att1, b1);

    // ---- layer 2 ----
    gemm_mfma<2><<<dim3(MT, 1), 256, 0, stream>>>();
    att_agg2<<<gN, 256, 0, stream>>>(att2, b2, (float*)d_out);
}

// Round 10
// 453.404 us; speedup vs baseline: 1.1795x; 1.1795x over previous
//
#include <hip/hip_runtime.h>

#define N_NODES 50000
#define M_PAD 50048            // 391 * 128
#define MT 391
#define F_IN 256
#define F_H 128
#define F_OUT 64
#define E_MAX 1600000
#define NEG_SLOPE 0.2f
#define EPS_F 1e-16f
#define NPART 196              // ceil(50000/256)
#define NBUCK 196              // coarse buckets: dst >> 8
#define CH_E 8192              // edges per sortA block -> 196 blocks

typedef __bf16 bf16x8 __attribute__((ext_vector_type(8)));
typedef float f32x4 __attribute__((ext_vector_type(4)));

// ---------------- device-global scratch ------------------------------------
__device__ unsigned short g_B1h[256 * 256];
__device__ unsigned short g_B1l[256 * 256];
__device__ unsigned short g_B2h[128 * 128];
__device__ unsigned short g_B2l[128 * 128];
__device__ unsigned short g_x1h[(size_t)M_PAD * F_IN];
__device__ unsigned short g_x1l[(size_t)M_PAD * F_IN];
__device__ unsigned short g_hh[(size_t)M_PAD * F_H];
__device__ unsigned short g_hl[(size_t)M_PAD * F_H];
// gather tables: xl in bf16 (halves gather bytes), xr in f32 (read once/dst)
__device__ unsigned short g_xl1b[(size_t)N_NODES * F_H];
__device__ float g_xr1[(size_t)N_NODES * F_H];
__device__ unsigned short g_xl2b[(size_t)N_NODES * F_OUT];
__device__ float g_xr2[(size_t)N_NODES * F_OUT];
// CSR by dst
__device__ unsigned g_cnt[N_NODES];
__device__ unsigned g_part[NPART];
__device__ unsigned g_rowstart[N_NODES + 1];
__device__ unsigned g_bcursor[NBUCK];
__device__ unsigned g_bucketed[E_MAX];     // packed src | dst<<16
__device__ int g_src_sorted[E_MAX];

// ---------------- helpers ---------------------------------------------------
__device__ inline float san(float v) { return fminf(fmaxf(v, -64.f), 64.f); }
__device__ inline float lrelu(float z) { return fmaxf(z, NEG_SLOPE * z); }
__device__ inline unsigned short f2bf(float f) {        // RNE f32->bf16
    unsigned u = __float_as_uint(f);
    return (unsigned short)((u + 0x7fffu + ((u >> 16) & 1u)) >> 16);
}
__device__ inline float bf2f(unsigned short h) {
    return __uint_as_float(((unsigned)h) << 16);
}
__device__ inline float blo(unsigned w) { return __uint_as_float(w << 16); }
__device__ inline float bhi(unsigned w) { return __uint_as_float(w & 0xffff0000u); }

// ---------------- weight prepack + csr_zero (fused) -------------------------
__global__ void wconv_all(const float* __restrict__ Wl1,
                          const float* __restrict__ Wr1,
                          const float* __restrict__ Wl2,
                          const float* __restrict__ Wr2) {
    int i = blockIdx.x * blockDim.x + threadIdx.x;
    if (i < N_NODES) g_cnt[i] = 0u;                    // fused csr_zero
    if (i < 256 * 256) {
        int n = i >> 8, k = i & 255;
        float v = san((n < 128) ? Wl1[k * 128 + n] : Wr1[k * 128 + (n - 128)]);
        unsigned short h = f2bf(v);
        g_B1h[n * 256 + k] = h;
        g_B1l[n * 256 + k] = f2bf(v - bf2f(h));
    }
    if (i < 128 * 128) {
        int n = i >> 7, k = i & 127;
        float v = san((n < 64) ? Wl2[k * 64 + n] : Wr2[k * 64 + (n - 64)]);
        unsigned short h = f2bf(v);
        g_B2h[n * 128 + k] = h;
        g_B2l[n * 128 + k] = f2bf(v - bf2f(h));
    }
}

// ---------------- x split + h pad-row zero (fused) --------------------------
__global__ void split_x(const float* __restrict__ x) {
    int i = blockIdx.x * 256 + threadIdx.x;
    if (i < (M_PAD - N_NODES) * F_H) {                 // fused pad_h
        g_hh[(size_t)N_NODES * F_H + i] = 0;
        g_hl[(size_t)N_NODES * F_H + i] = 0;
    }
    int m = i >> 6, c4 = i & 63;
    float4 v = make_float4(0.f, 0.f, 0.f, 0.f);
    if (m < N_NODES) v = ((const float4*)(x + (size_t)m * F_IN))[c4];
    v.x = san(v.x); v.y = san(v.y); v.z = san(v.z); v.w = san(v.w);
    unsigned short h0 = f2bf(v.x), h1 = f2bf(v.y), h2 = f2bf(v.z), h3 = f2bf(v.w);
    unsigned short l0 = f2bf(v.x - bf2f(h0)), l1 = f2bf(v.y - bf2f(h1));
    unsigned short l2 = f2bf(v.z - bf2f(h2)), l3 = f2bf(v.w - bf2f(h3));
    size_t o = (size_t)m * F_IN + c4 * 4;
    uint2 ph = make_uint2(((unsigned)h1 << 16) | h0, ((unsigned)h3 << 16) | h2);
    uint2 pl = make_uint2(((unsigned)l1 << 16) | l0, ((unsigned)l3 << 16) | l2);
    *(uint2*)(g_x1h + o) = ph;
    *(uint2*)(g_x1l + o) = pl;
}

// ---------------- CSR build --------------------------------------------------
__global__ void csr_hist(const int* __restrict__ dst, int E) {
    int e = blockIdx.x * blockDim.x + threadIdx.x;
    if (e < E) atomicAdd(&g_cnt[dst[e]], 1u);
}
__global__ __launch_bounds__(256) void scanA() {
    int i = blockIdx.x * 256 + threadIdx.x;
    unsigned v = (i < N_NODES) ? g_cnt[i] : 0u;
#pragma unroll
    for (int off = 32; off > 0; off >>= 1) v += __shfl_xor(v, off, 64);
    __shared__ unsigned ws[4];
    if ((threadIdx.x & 63) == 0) ws[threadIdx.x >> 6] = v;
    __syncthreads();
    if (threadIdx.x == 0) g_part[blockIdx.x] = ws[0] + ws[1] + ws[2] + ws[3];
}
__global__ __launch_bounds__(256) void scanB(int E) {
    __shared__ unsigned lds[256];
    int t = threadIdx.x;
    unsigned v = (t < NPART) ? g_part[t] : 0u;
    lds[t] = v;
    __syncthreads();
    for (int off = 1; off < 256; off <<= 1) {
        unsigned u = (t >= off) ? lds[t - off] : 0u;
        __syncthreads();
        lds[t] += u;
        __syncthreads();
    }
    if (t < NPART) {
        unsigned excl = lds[t] - v;
        g_part[t] = excl;
        g_bcursor[t] = excl;               // fused binit (bucket start == part)
    }
    if (t == 0) g_rowstart[N_NODES] = (unsigned)E;
}
__global__ __launch_bounds__(256) void scanC() {
    __shared__ unsigned lds[256];
    int t = threadIdx.x;
    int i = blockIdx.x * 256 + t;
    unsigned v = (i < N_NODES) ? g_cnt[i] : 0u;
    lds[t] = v;
    __syncthreads();
    for (int off = 1; off < 256; off <<= 1) {
        unsigned u = (t >= off) ? lds[t - off] : 0u;
        __syncthreads();
        lds[t] += u;
        __syncthreads();
    }
    if (i < N_NODES) g_rowstart[i] = lds[t] - v + g_part[blockIdx.x];
}

// ---------------- two-pass locality-aware sort ------------------------------
__global__ __launch_bounds__(256) void sortA(const int* __restrict__ src,
                                             const int* __restrict__ dst, int E) {
    __shared__ unsigned l_cnt[4][NBUCK];   // counts, then per-wave cursors
    int t = threadIdx.x, w = t >> 6;
    int e0 = blockIdx.x * CH_E;
    int e1 = min(e0 + CH_E, E);
    for (int i = t; i < 4 * NBUCK; i += 256) (&l_cnt[0][0])[i] = 0u;
    __syncthreads();
    for (int e = e0 + t; e < e1; e += 256)
        atomicAdd(&l_cnt[w][dst[e] >> 8], 1u);
    __syncthreads();
    for (int b = t; b < NBUCK; b += 256) {
        unsigned c0 = l_cnt[0][b], c1 = l_cnt[1][b], c2 = l_cnt[2][b], c3 = l_cnt[3][b];
        unsigned tot = c0 + c1 + c2 + c3;
        unsigned base = tot ? atomicAdd(&g_bcursor[b], tot) : 0u;
        l_cnt[0][b] = base;
        l_cnt[1][b] = base + c0;
        l_cnt[2][b] = base + c0 + c1;
        l_cnt[3][b] = base + c0 + c1 + c2;
    }
    __syncthreads();
    for (int e = e0 + t; e < e1; e += 256) {
        int d = dst[e];
        int b = d >> 8;
        unsigned pos = atomicAdd(&l_cnt[w][b], 1u);
        g_bucketed[pos] = (unsigned)src[e] | ((unsigned)d << 16);
    }
}
__global__ __launch_bounds__(256) void sortB() {
    __shared__ unsigned l_cur[256];
    int b = blockIdx.x;
    int d0 = b * 256;
    int t = threadIdx.x;
    l_cur[t] = g_rowstart[min(d0 + t, N_NODES)];
    unsigned bstart = g_rowstart[min(d0, N_NODES)];
    unsigned bend   = g_rowstart[min(d0 + 256, N_NODES)];
    __syncthreads();
    for (unsigned i = bstart + t; i < bend; i += 256) {
        unsigned e = g_bucketed[i];
        unsigned d = e >> 16;
        unsigned pos = atomicAdd(&l_cur[d - d0], 1u);
        g_src_sorted[pos] = (int)(e & 0xFFFFu);
    }
}

// ---------------- split-bf16 MFMA GEMM --------------------------------------
// Grid: (N-blocks, M-blocks) with N fastest-varying so the blocks sharing an
// A-tile dispatch adjacently (L2 reuse of A). No register prefetch (round-9
// P[] spilled to scratch: +180 MB HBM traffic).
template<int LAYER>
__global__ __launch_bounds__(256) void gemm_mfma() {
    constexpr int K    = (LAYER == 1) ? 256 : 128;
    constexpr int NSPL = (LAYER == 1) ? 128 : 64;
    const unsigned short* __restrict__ Ah = (LAYER == 1) ? g_x1h : g_hh;
    const unsigned short* __restrict__ Al = (LAYER == 1) ? g_x1l : g_hl;
    const unsigned short* __restrict__ Bh = (LAYER == 1) ? g_B1h : g_B2h;
    const unsigned short* __restrict__ Bl = (LAYER == 1) ? g_B1l : g_B2l;
    unsigned short* __restrict__ OL = (LAYER == 1) ? g_xl1b : g_xl2b;
    float* __restrict__ OR_ = (LAYER == 1) ? g_xr1 : g_xr2;

    __shared__ __align__(16) unsigned short As_h[128][40];
    __shared__ __align__(16) unsigned short As_l[128][40];
    __shared__ __align__(16) unsigned short Bs_h[128][40];
    __shared__ __align__(16) unsigned short Bs_l[128][40];

    const int m0 = blockIdx.y * 128;          // M from y (slow axis)
    const int n0 = blockIdx.x * 128;          // N from x (fast axis)
    const int t = threadIdx.x;
    const int wave = t >> 6, lane = t & 63;
    const int wm = (wave >> 1) * 64, wn = (wave & 1) * 64;
    const int lr = lane & 15, g8 = (lane >> 4) * 8;
    const int srow = t >> 1, shalf = (t & 1) * 16;

    f32x4 acc[4][4];
#pragma unroll
    for (int i = 0; i < 4; ++i)
#pragma unroll
        for (int j = 0; j < 4; ++j) acc[i][j] = (f32x4){0.f, 0.f, 0.f, 0.f};

    for (int kb = 0; kb < K; kb += 32) {
        __syncthreads();
        {
            size_t ga = (size_t)(m0 + srow) * K + kb + shalf;
            *(uint4*)&As_h[srow][shalf]     = *(const uint4*)(Ah + ga);
            *(uint4*)&As_h[srow][shalf + 8] = *(const uint4*)(Ah + ga + 8);
            *(uint4*)&As_l[srow][shalf]     = *(const uint4*)(Al + ga);
            *(uint4*)&As_l[srow][shalf + 8] = *(const uint4*)(Al + ga + 8);
            size_t gb = (size_t)(n0 + srow) * K + kb + shalf;
            *(uint4*)&Bs_h[srow][shalf]     = *(const uint4*)(Bh + gb);
            *(uint4*)&Bs_h[srow][shalf + 8] = *(const uint4*)(Bh + gb + 8);
            *(uint4*)&Bs_l[srow][shalf]     = *(const uint4*)(Bl + gb);
            *(uint4*)&Bs_l[srow][shalf + 8] = *(const uint4*)(Bl + gb + 8);
        }
        __syncthreads();

        bf16x8 af_h[4], af_l[4], bf_h[4], bf_l[4];
#pragma unroll
        for (int i = 0; i < 4; ++i) {
            af_h[i] = *(const bf16x8*)&As_h[wm + i * 16 + lr][g8];
            af_l[i] = *(const bf16x8*)&As_l[wm + i * 16 + lr][g8];
        }
#pragma unroll
        for (int j = 0; j < 4; ++j) {
            bf_h[j] = *(const bf16x8*)&Bs_h[wn + j * 16 + lr][g8];
            bf_l[j] = *(const bf16x8*)&Bs_l[wn + j * 16 + lr][g8];
        }
#pragma unroll
        for (int i = 0; i < 4; ++i)
#pragma unroll
            for (int j = 0; j < 4; ++j) {
                acc[i][j] = __builtin_amdgcn_mfma_f32_16x16x32_bf16(af_h[i], bf_h[j], acc[i][j], 0, 0, 0);
                acc[i][j] = __builtin_amdgcn_mfma_f32_16x16x32_bf16(af_h[i], bf_l[j], acc[i][j], 0, 0, 0);
                acc[i][j] = __builtin_amdgcn_mfma_f32_16x16x32_bf16(af_l[i], bf_h[j], acc[i][j], 0, 0, 0);
            }
    }

    const int drow = (lane >> 4) * 4;
#pragma unroll
    for (int i = 0; i < 4; ++i)
#pragma unroll
        for (int j = 0; j < 4; ++j) {
            int gn = n0 + wn + j * 16 + lr;
#pragma unroll
            for (int r = 0; r < 4; ++r) {
                int m = m0 + wm + i * 16 + drow + r;
                if (m < N_NODES) {
                    if (gn < NSPL) OL[(size_t)m * NSPL + gn] = f2bf(acc[i][j][r]);
                    else           OR_[(size_t)m * NSPL + (gn - NSPL)] = acc[i][j][r];
                }
            }
        }
}

// ---------------- fused attention+aggregate, layer 1 ------------------------
__global__ __launch_bounds__(256) void att_agg1(const float* __restrict__ att,
                                                const float* __restrict__ bias) {
    __shared__ float s_out[4][F_H];
    int wid = threadIdx.x >> 6, lane = threadIdx.x & 63;
    int w = blockIdx.x * 4 + wid;
    int g = lane >> 3;
    int fi = lane & 7;
    int f0 = fi * 16;

    float4 xr[4], at[4];
    const float4* xrp = (const float4*)(g_xr1 + (size_t)w * F_H + f0);
    const float4* atp = (const float4*)(att + f0);
#pragma unroll
    for (int q = 0; q < 4; ++q) {
        xr[q] = xrp[q];
        float4 a = atp[q];
        a.x = san(a.x); a.y = san(a.y); a.z = san(a.z); a.w = san(a.w);
        at[q] = a;
    }

    int beg = (int)g_rowstart[w], end = (int)g_rowstart[w + 1];
    float m = -INFINITY, ssum = 0.f;
    float4 acc[4];
#pragma unroll
    for (int q = 0; q < 4; ++q) acc[q] = make_float4(0.f, 0.f, 0.f, 0.f);

    for (int c0 = beg; c0 < end; c0 += 64) {
        int nc = min(64, end - c0);
        int mysrc = (lane < nc) ? g_src_sorted[c0 + lane] : 0;
        for (int r0 = 0; r0 < nc; r0 += 8) {
            int eidx = r0 + g;
            bool valid = eidx < nc;
            int s = __shfl(mysrc, eidx, 64);
            const uint4* rowp = (const uint4*)(g_xl1b + (size_t)s * F_H + f0);
            uint4 u0 = rowp[0], u1 = rowp[1];
            float4 row[4];
            row[0] = make_float4(blo(u0.x), bhi(u0.x), blo(u0.y), bhi(u0.y));
            row[1] = make_float4(blo(u0.z), bhi(u0.z), blo(u0.w), bhi(u0.w));
            row[2] = make_float4(blo(u1.x), bhi(u1.x), blo(u1.y), bhi(u1.y));
            row[3] = make_float4(blo(u1.z), bhi(u1.z), blo(u1.w), bhi(u1.w));
            float d = 0.f;
#pragma unroll
            for (int q = 0; q < 4; ++q) {
                float z;
                z = row[q].x + xr[q].x; d = fmaf(lrelu(z), at[q].x, d);
                z = row[q].y + xr[q].y; d = fmaf(lrelu(z), at[q].y, d);
                z = row[q].z + xr[q].z; d = fmaf(lrelu(z), at[q].z, d);
                z = row[q].w + xr[q].w; d = fmaf(lrelu(z), at[q].w, d);
            }
            d += __shfl_xor(d, 1, 64);
            d += __shfl_xor(d, 2, 64);
            d += __shfl_xor(d, 4, 64);
            float e = valid ? d : -INFINITY;
            float M = e;
            M = fmaxf(M, __shfl_xor(M, 8, 64));
            M = fmaxf(M, __shfl_xor(M, 16, 64));
            M = fmaxf(M, __shfl_xor(M, 32, 64));
            if (M > m) {                      // wave-uniform; skipping is exact
                float sc = __expf(m - M);     // 0 on first round (m=-inf)
                m = M;
                ssum *= sc;
#pragma unroll
                for (int q = 0; q < 4; ++q) {
                    acc[q].x *= sc; acc[q].y *= sc;
                    acc[q].z *= sc; acc[q].w *= sc;
                }
            }
            float p = __expf(e - m);          // 0 for invalid edges
            ssum += p;
#pragma unroll
            for (int q = 0; q < 4; ++q) {
                acc[q].x = fmaf(p, row[q].x, acc[q].x);
                acc[q].y = fmaf(p, row[q].y, acc[q].y);
                acc[q].z = fmaf(p, row[q].z, acc[q].z);
                acc[q].w = fmaf(p, row[q].w, acc[q].w);
            }
        }
    }
#pragma unroll
    for (int off = 8; off < 64; off <<= 1) {
        ssum += __shfl_xor(ssum, off, 64);
#pragma unroll
        for (int q = 0; q < 4; ++q) {
            acc[q].x += __shfl_xor(acc[q].x, off, 64);
            acc[q].y += __shfl_xor(acc[q].y, off, 64);
            acc[q].z += __shfl_xor(acc[q].z, off, 64);
            acc[q].w += __shfl_xor(acc[q].w, off, 64);
        }
    }
    float inv = 1.f / (ssum + EPS_F);
    if (g == 0) {
        float4* op = (float4*)&s_out[wid][f0];
#pragma unroll
        for (int q = 0; q < 4; ++q) {
            float4 v;
            v.x = acc[q].x * inv; v.y = acc[q].y * inv;
            v.z = acc[q].z * inv; v.w = acc[q].w * inv;
            op[q] = v;
        }
    }
    __syncthreads();
    int f2 = lane * 2;
    float2 o = *(float2*)&s_out[wid][f2];
    o.x = fmaxf(o.x + san(bias[f2]), 0.f);
    o.y = fmaxf(o.y + san(bias[f2 + 1]), 0.f);
    unsigned short hx = f2bf(o.x), hy = f2bf(o.y);
    unsigned short lx = f2bf(o.x - bf2f(hx)), ly = f2bf(o.y - bf2f(hy));
    size_t base = (size_t)w * F_H + f2;
    *(unsigned*)(g_hh + base) = ((unsigned)hy << 16) | hx;
    *(unsigned*)(g_hl + base) = ((unsigned)ly << 16) | lx;
}

// ---------------- fused attention+aggregate, layer 2 (F=64) -----------------
__global__ __launch_bounds__(256) void att_agg2(const float* __restrict__ att,
                                                const float* __restrict__ bias,
                                                float* __restrict__ out) {
    __shared__ float s_out[4][F_OUT];
    int wid = threadIdx.x >> 6, lane = threadIdx.x & 63;
    int w = blockIdx.x * 4 + wid;
    int g = lane >> 3;
    int fi = lane & 7;
    int f0 = fi * 8;

    float4 xr[2], at[2];
    const float4* xrp = (const float4*)(g_xr2 + (size_t)w * F_OUT + f0);
    const float4* atp = (const float4*)(att + f0);
#pragma unroll
    for (int q = 0; q < 2; ++q) {
        xr[q] = xrp[q];
        float4 a = atp[q];
        a.x = san(a.x); a.y = san(a.y); a.z = san(a.z); a.w = san(a.w);
        at[q] = a;
    }

    int beg = (int)g_rowstart[w], end = (int)g_rowstart[w + 1];
    float m = -INFINITY, ssum = 0.f;
    float4 acc[2];
#pragma unroll
    for (int q = 0; q < 2; ++q) acc[q] = make_float4(0.f, 0.f, 0.f, 0.f);

    for (int c0 = beg; c0 < end; c0 += 64) {
        int nc = min(64, end - c0);
        int mysrc = (lane < nc) ? g_src_sorted[c0 + lane] : 0;
        for (int r0 = 0; r0 < nc; r0 += 8) {
            int eidx = r0 + g;
            bool valid = eidx < nc;
            int s = __shfl(mysrc, eidx, 64);
            uint4 u0 = *(const uint4*)(g_xl2b + (size_t)s * F_OUT + f0);
            float4 row[2];
            row[0] = make_float4(blo(u0.x), bhi(u0.x), blo(u0.y), bhi(u0.y));
            row[1] = make_float4(blo(u0.z), bhi(u0.z), blo(u0.w), bhi(u0.w));
            float d = 0.f;
#pragma unroll
            for (int q = 0; q < 2; ++q) {
                float z;
                z = row[q].x + xr[q].x; d = fmaf(lrelu(z), at[q].x, d);
                z = row[q].y + xr[q].y; d = fmaf(lrelu(z), at[q].y, d);
                z = row[q].z + xr[q].z; d = fmaf(lrelu(z), at[q].z, d);
                z = row[q].w + xr[q].w; d = fmaf(lrelu(z), at[q].w, d);
            }
            d += __shfl_xor(d, 1, 64);
            d += __shfl_xor(d, 2, 64);
            d += __shfl_xor(d, 4, 64);
            float e = valid ? d : -INFINITY;
            float M = e;
            M = fmaxf(M, __shfl_xor(M, 8, 64));
            M = fmaxf(M, __shfl_xor(M, 16, 64));
            M = fmaxf(M, __shfl_xor(M, 32, 64));
            if (M > m) {
                float sc = __expf(m - M);
                m = M;
                ssum *= sc;
#pragma unroll
                for (int q = 0; q < 2; ++q) {
                    acc[q].x *= sc; acc[q].y *= sc;
                    acc[q].z *= sc; acc[q].w *= sc;
                }
            }
            float p = __expf(e - m);
            ssum += p;
#pragma unroll
            for (int q = 0; q < 2; ++q) {
                acc[q].x = fmaf(p, row[q].x, acc[q].x);
                acc[q].y = fmaf(p, row[q].y, acc[q].y);
                acc[q].z = fmaf(p, row[q].z, acc[q].z);
                acc[q].w = fmaf(p, row[q].w, acc[q].w);
            }
        }
    }
#pragma unroll
    for (int off = 8; off < 64; off <<= 1) {
        ssum += __shfl_xor(ssum, off, 64);
#pragma unroll
        for (int q = 0; q < 2; ++q) {
            acc[q].x += __shfl_xor(acc[q].x, off, 64);
            acc[q].y += __shfl_xor(acc[q].y, off, 64);
            acc[q].z += __shfl_xor(acc[q].z, off, 64);
            acc[q].w += __shfl_xor(acc[q].w, off, 64);
        }
    }
    float inv = 1.f / (ssum + EPS_F);
    if (g == 0) {
        float4* op = (float4*)&s_out[wid][f0];
#pragma unroll
        for (int q = 0; q < 2; ++q) {
            float4 v;
            v.x = acc[q].x * inv; v.y = acc[q].y * inv;
            v.z = acc[q].z * inv; v.w = acc[q].w * inv;
            op[q] = v;
        }
    }
    __syncthreads();
    out[(size_t)w * F_OUT + lane] = s_out[wid][lane] + san(bias[lane]);
}

// ---------------- launch ------------------------------------------------------
extern "C" void kernel_launch(void* const* d_in, const int* in_sizes, int n_in,
                              void* d_out, int out_size, void* d_ws, size_t ws_size,
                              hipStream_t stream) {
    const float* x    = (const float*)d_in[0];
    const int*   ei   = (const int*)d_in[1];
    const float* Wl1  = (const float*)d_in[2];
    const float* Wr1  = (const float*)d_in[3];
    const float* att1 = (const float*)d_in[4];
    const float* b1   = (const float*)d_in[5];
    const float* Wl2  = (const float*)d_in[6];
    const float* Wr2  = (const float*)d_in[7];
    const float* att2 = (const float*)d_in[8];
    const float* b2   = (const float*)d_in[9];

    int E = in_sizes[1] / 2;
    const int* src = ei;
    const int* dst = ei + E;

    int gE = (E + 255) / 256;
    int gN = N_NODES / 4;
    int gSX = (M_PAD * (F_IN / 4)) / 256;
    int gSA = (E + CH_E - 1) / CH_E;

    wconv_all<<<256, 256, 0, stream>>>(Wl1, Wr1, Wl2, Wr2);   // + csr_zero
    split_x<<<gSX, 256, 0, stream>>>(x);                      // + pad_h

    csr_hist<<<gE, 256, 0, stream>>>(dst, E);
    scanA<<<NPART, 256, 0, stream>>>();
    scanB<<<1, 256, 0, stream>>>(E);                          // + binit
    scanC<<<NPART, 256, 0, stream>>>();
    sortA<<<gSA, 256, 0, stream>>>(src, dst, E);
    sortB<<<NBUCK, 256, 0, stream>>>();

    // ---- layer 1 ----  (N-blocks on x: adjacent dispatch shares A-tile in L2)
    gemm_mfma<1><<<dim3(2, MT), 256, 0, stream>>>();
    att_agg1<<<gN, 256, 0, stream>>>(att1, b1);

    // ---- layer 2 ----
    gemm_mfma<2><<<dim3(1, MT), 256, 0, stream>>>();
    att_agg2<<<gN, 256, 0, stream>>>(att2, b2, (float*)d_out);
}